// Round 1
// baseline (112.332 us; speedup 1.0000x reference)
//
#include <hip/hip_runtime.h>

#define WIDTH  262144
#define OUTW   (WIDTH - 31)         // 262113
#define WTILE  512                  // outputs per slice
#define NSW    560                  // staged elements per slice (512 + 48 halo)
#define SCALE_V 0.17782794100389229f // sqrt(10^(-15/10))

#define TBL_N    1024
#define TBL_MAX  10.0f
#define TBL_SCL  (TBL_N / TBL_MAX)   // 102.4

typedef _Float16 half8  __attribute__((ext_vector_type(8)));
typedef _Float16 half4v __attribute__((ext_vector_type(4)));
typedef float    floatx4 __attribute__((ext_vector_type(4)));

__device__ __forceinline__ float wload(const float* __restrict__ w, int t) {
    return (t >= 0 && t < 32) ? w[t] : 0.0f;
}

// fast tanh via one v_exp_f32: tanh(x) = (e^2x - 1)/(e^2x + 1).
// |x| clamped to 9 (tanh(9) = 1 - 2e-8); abs err ~1e-7, far below the
// ~1e-4 f16-FIR quantization that dominates absmax.
__device__ __forceinline__ float fast_tanhf(float x) {
    const float xc = fminf(fmaxf(x, -9.0f), 9.0f);
    const float a  = __expf(2.0f * xc);
    return (a - 1.0f) / (a + 1.0f);
}

#define MFMA16(A, B, C) __builtin_amdgcn_mfma_f32_16x16x32_f16((A), (B), (C), 0, 0, 0)

// Single fused kernel: no workspace, no table-fill pre-kernel. Each block
// rebuilds the 1025-point s-table (s(mag) = sum_f w2[f]*tanh(w1[f]*mag)/mag)
// in LDS itself — 256 threads x 4 points x 8 fast-tanh, issued AFTER the
// slice-0 global prefetch so the VALU burst hides under HBM latency.
// Software-pipelined wave-private pipeline: each wave handles 2 consecutive
// 512-output slices; slice-1 loads prefetched before slice-0's MFMA+epilogue.
// One __syncthreads total (s_val visibility).
__global__ __launch_bounds__(256, 4) void fused_hammer_mfma(
    const float* __restrict__ xr_g,   const float* __restrict__ xi_g,
    const float* __restrict__ w1_pre, const float* __restrict__ w2_pre,
    const float* __restrict__ wfr,    const float* __restrict__ wfi,
    const float* __restrict__ w1_post,const float* __restrict__ b1_post,
    const float* __restrict__ w2_post,const float* __restrict__ b2_post,
    float* __restrict__ out)
{
    __shared__ __align__(16) _Float16 s_rh[4][NSW];
    __shared__ __align__(16) _Float16 s_rl[4][NSW];
    __shared__ __align__(16) _Float16 s_ih[4][NSW];
    __shared__ __align__(16) _Float16 s_il[4][NSW];
    __shared__ __align__(16) float    s_val[TBL_N + 4];   // 1025 points used

    const int tid    = threadIdx.x;
    const int lane   = tid & 63;
    const int wv     = tid >> 6;
    const int brow   = blockIdx.y;
    const long rowbase = (long)brow * WIDTH;
    const int wbase  = blockIdx.x * 4096 + wv * 1024;  // wave's first slice offset

    // ---- prefetch slice 0 FIRST (2 float4-pairs per lane; branchless clamp) ----
    const int g0 = min(wbase       + 4 * lane, WIDTH - 4);
    const int g1 = min(wbase + 256 + 4 * lane, WIDTH - 4);
    float4 p_r0 = *(const float4*)(xr_g + rowbase + g0);
    float4 p_i0 = *(const float4*)(xi_g + rowbase + g0);
    float4 p_r1 = *(const float4*)(xr_g + rowbase + g1);
    float4 p_i1 = *(const float4*)(xi_g + rowbase + g1);

    // ---- build s-table in LDS (VALU work overlaps the prefetch latency) ----
    {
        float tw1[8], tw2[8];
#pragma unroll
        for (int f = 0; f < 8; ++f) { tw1[f] = w1_pre[f]; tw2[f] = w2_pre[f]; }
#pragma unroll
        for (int jj = 0; jj < 5; ++jj) {
            const int j = tid + 256 * jj;
            if (j <= TBL_N) {
                float s;
                if (j == 0) {
                    s = 0.f;                                // tanh'(0)=1 limit
#pragma unroll
                    for (int f = 0; f < 8; ++f) s = fmaf(tw2[f], tw1[f], s);
                } else {
                    const float mag = (float)j * (1.0f / TBL_SCL);
                    float m = 0.f;
#pragma unroll
                    for (int f = 0; f < 8; ++f)
                        m = fmaf(tw2[f], fast_tanhf(tw1[f] * mag), m);
                    s = m / mag;
                }
                s_val[j] = s;
            }
        }
    }

    // ---- post-MLP uniform weights ----
    float w1p[8], b1p[8], w2p[8];
#pragma unroll
    for (int f = 0; f < 8; ++f) { w1p[f] = w1_post[f]; b1p[f] = b1_post[f]; w2p[f] = w2_post[f]; }
    const float b2p = b2_post[0];

    // ---- build Toeplitz weight fragments (hi/lo f16), once per lane ----
    const int jA = lane & 15;
    const int kg = lane >> 4;
    half8 A1r_h, A1r_l, A1mi_h, A1mi_l, A1i_h, A1i_l, A2r_h, A2r_l, A2i_h, A2i_l;
#pragma unroll
    for (int jj = 0; jj < 8; ++jj) {
        const int k  = 8 * kg + jj;
        const int t1 = k - jA;
        const float wr1 = wload(wfr, t1);
        const float wi1 = wload(wfi, t1);
        const int t2 = (k < 16) ? (k + 32 - jA) : (k + 16 - jA);
        const float wr2 = wload(wfr, t2);
        const float wi2 = wload(wfi, t2);
        const float a2r = (k < 16) ? wr2 : -wi2;   // zr second chunk: [wr | -wi]
        const float a2i = (k < 16) ? wi2 : wr2;    // zi second chunk: [wi |  wr]
        _Float16 h;
        h = (_Float16)wr1;   A1r_h[jj]  = h; A1r_l[jj]  = (_Float16)(wr1 - (float)h);
        h = (_Float16)(-wi1);A1mi_h[jj] = h; A1mi_l[jj] = (_Float16)(-wi1 - (float)h);
        h = (_Float16)wi1;   A1i_h[jj]  = h; A1i_l[jj]  = (_Float16)(wi1 - (float)h);
        h = (_Float16)a2r;   A2r_h[jj]  = h; A2r_l[jj]  = (_Float16)(a2r - (float)h);
        h = (_Float16)a2i;   A2i_h[jj]  = h; A2i_l[jj]  = (_Float16)(a2i - (float)h);
    }

    __syncthreads();   // s_val visible to all waves; only barrier in the kernel

    const bool row_aligned = ((brow & 1) == 0);   // even brow -> 16B-aligned stores

    // stage one float4-pair into strip group p (table lerp + f16 hi/lo split)
#define STAGE4(VR, VI, P)                                                     \
    do {                                                                      \
        const float* vrf = &(VR).x;                                           \
        const float* vif = &(VI).x;                                           \
        half4v rh_, rl_, ih_, il_;                                            \
        _Pragma("unroll")                                                     \
        for (int e = 0; e < 4; ++e) {                                         \
            const float r  = vrf[e], im = vif[e];                             \
            const float sq  = fmaf(r, r, im * im);                            \
            const float mag = __builtin_sqrtf(sq);                            \
            const float t   = fminf(mag * TBL_SCL, (float)(TBL_N - 1) + 0.999f); \
            const int   i0  = (int)t;                                         \
            const float frac = t - (float)i0;                                 \
            const float sA  = s_val[i0];                                      \
            const float sB  = s_val[i0 + 1];                                  \
            const float s   = fmaf(frac, sB - sA, sA);                        \
            const float xhr = s * r;                                          \
            const float xhi = s * im;                                         \
            const _Float16 hr = (_Float16)xhr;                                \
            const _Float16 hi = (_Float16)xhi;                                \
            rh_[e] = hr; rl_[e] = (_Float16)(xhr - (float)hr);                \
            ih_[e] = hi; il_[e] = (_Float16)(xhi - (float)hi);                \
        }                                                                     \
        *(half4v*)&s_rh[wv][4 * (P)] = rh_;                                   \
        *(half4v*)&s_rl[wv][4 * (P)] = rl_;                                   \
        *(half4v*)&s_ih[wv][4 * (P)] = ih_;                                   \
        *(half4v*)&s_il[wv][4 * (P)] = il_;                                   \
    } while (0)

#pragma unroll
    for (int q = 0; q < 2; ++q) {
        const int wstart = wbase + q * WTILE;

        // halo pair (strip groups 128..139, lanes 0..11 only)
        float4 h_r, h_i;
        if (lane < 12) {
            const int g2 = min(wstart + 512 + 4 * lane, WIDTH - 4);
            h_r = *(const float4*)(xr_g + rowbase + g2);
            h_i = *(const float4*)(xi_g + rowbase + g2);
        }

        STAGE4(p_r0, p_i0, lane);
        STAGE4(p_r1, p_i1, 64 + lane);

        if (q == 0) {   // prefetch slice 1 while slice 0 computes below
            const int n0 = min(wbase + 512       + 4 * lane, WIDTH - 4);
            const int n1 = min(wbase + 512 + 256 + 4 * lane, WIDTH - 4);
            p_r0 = *(const float4*)(xr_g + rowbase + n0);
            p_i0 = *(const float4*)(xi_g + rowbase + n0);
            p_r1 = *(const float4*)(xr_g + rowbase + n1);
            p_i1 = *(const float4*)(xi_g + rowbase + n1);
        }

        if (lane < 12) STAGE4(h_r, h_i, 128 + lane);

        // wave-private LDS: own writes complete -> readable, no block barrier
        asm volatile("s_waitcnt lgkmcnt(0)" ::: "memory");

        // ---- MFMA FIR + post-MLP epilogue, 2 tiles of 256 outputs ----
#pragma unroll
        for (int tt = 0; tt < 2; ++tt) {
            const int base_o = 256 * tt;
            const int i1 = base_o + 16 * jA + 8 * kg;          // B1 elements
            const half8 Bxr_h = *(const half8*)&s_rh[wv][i1];
            const half8 Bxi_h = *(const half8*)&s_ih[wv][i1];
            const half8 Bxr_l = *(const half8*)&s_rl[wv][i1];
            const half8 Bxi_l = *(const half8*)&s_il[wv][i1];
            const int i2 = base_o + 16 * jA + 32 + 8 * (kg & 1); // B2 mixed
            const _Float16* srcH = (kg < 2) ? s_rh[wv] : s_ih[wv];
            const _Float16* srcL = (kg < 2) ? s_rl[wv] : s_il[wv];
            const half8 Bmx_h = *(const half8*)&srcH[i2];
            const half8 Bmx_l = *(const half8*)&srcL[i2];

            floatx4 accr = {0.f, 0.f, 0.f, 0.f};
            floatx4 acci = {0.f, 0.f, 0.f, 0.f};
            accr = MFMA16(A1r_h,  Bxr_h, accr);  acci = MFMA16(A1i_h,  Bxr_h, acci);
            accr = MFMA16(A1mi_h, Bxi_h, accr);  acci = MFMA16(A1r_h,  Bxi_h, acci);
            accr = MFMA16(A2r_h,  Bmx_h, accr);  acci = MFMA16(A2i_h,  Bmx_h, acci);
            accr = MFMA16(A1r_h,  Bxr_l, accr);  acci = MFMA16(A1i_h,  Bxr_l, acci);
            accr = MFMA16(A1mi_h, Bxi_l, accr);  acci = MFMA16(A1r_h,  Bxi_l, acci);
            accr = MFMA16(A2r_h,  Bmx_l, accr);  acci = MFMA16(A2i_h,  Bmx_l, acci);
            accr = MFMA16(A1r_l,  Bxr_h, accr);  acci = MFMA16(A1i_l,  Bxr_h, acci);
            accr = MFMA16(A1mi_l, Bxi_h, accr);  acci = MFMA16(A1r_l,  Bxi_h, acci);
            accr = MFMA16(A2r_l,  Bmx_h, accr);  acci = MFMA16(A2i_l,  Bmx_h, acci);

            // epilogue: lane owns 4 CONSECUTIVE outputs obase..obase+3
            const int obase = wstart + base_o + 16 * jA + 4 * kg;
            float ox[8];
#pragma unroll
            for (int r = 0; r < 4; ++r) {
                const float zr  = accr[r], zi = acci[r];
                const float zsq = fmaf(zr, zr, zi * zi);
                const float rs  = (zsq > 0.f) ? __builtin_amdgcn_rsqf(zsq) : 0.f;
                const float zmag = zsq * rs;
                float zm = b2p;
#pragma unroll
                for (int f = 0; f < 8; ++f) {
                    const float gfv = fmaf(zmag, w1p[f], b1p[f]);
                    zm = fmaf(fmaxf(gfv, 0.f), w2p[f], zm);
                }
                const float t = SCALE_V * zm * rs;
                ox[2 * r]     = (zsq > 0.f) ? t * zr : SCALE_V * zm;
                ox[2 * r + 1] = t * zi;
            }
            float* po = &out[((long)brow * OUTW + obase) * 2];
            if (obase + 3 < OUTW) {
                if (row_aligned) {
                    *(float4*)(po)     = make_float4(ox[0], ox[1], ox[2], ox[3]);
                    *(float4*)(po + 4) = make_float4(ox[4], ox[5], ox[6], ox[7]);
                } else {
#pragma unroll
                    for (int r = 0; r < 4; ++r)
                        *(float2*)(po + 2 * r) = make_float2(ox[2 * r], ox[2 * r + 1]);
                }
            } else {
#pragma unroll
                for (int r = 0; r < 4; ++r)
                    if (obase + r < OUTW)
                        *(float2*)(po + 2 * r) = make_float2(ox[2 * r], ox[2 * r + 1]);
            }
        }
    }
#undef STAGE4
}

extern "C" void kernel_launch(void* const* d_in, const int* in_sizes, int n_in,
                              void* d_out, int out_size, void* d_ws, size_t ws_size,
                              hipStream_t stream) {
    (void)d_ws; (void)ws_size;      // workspace intentionally unused
    dim3 grid(64, 16);              // 64 blocks/row x 16 rows; 4096 outputs/block
    fused_hammer_mfma<<<grid, 256, 0, stream>>>(
        (const float*)d_in[0], (const float*)d_in[1],
        (const float*)d_in[2], (const float*)d_in[3],
        (const float*)d_in[4], (const float*)d_in[5],
        (const float*)d_in[6], (const float*)d_in[7],
        (const float*)d_in[8], (const float*)d_in[9],
        (float*)d_out);
}